// Round 9
// baseline (299.698 us; speedup 1.0000x reference)
//
#include <hip/hip_runtime.h>
#include <hip/hip_cooperative_groups.h>
#include <math.h>

namespace cg = cooperative_groups;

#define BATCH      128
#define N_ATOMS    4096
#define NB         4095
#define NA         4094
#define NT         4093
#define FSTRIDE    184185              // floats per sample (odd!)
#define TOTAL_F4   5893920u            // 128*184185/4 (exact)
#define EPSV       1e-8f
#define THREADS    1024
#define WAVES      16
#define TILE_F     1080                // lcm-aligned: 40 bonds / 30 angles / 24 tors / 40 atoms
#define NTILES     171
#define SCR_F4     272
#define GRID       256                 // 1 block/CU, cooperative co-residency

#define PLANE      (BATCH * N_ATOMS)   // ws: 3 coord planes = 6 MB total

// Zero-cost compiler fence for the wave-private LDS scratch round-trip.
// Cross-lane store->read dep is invisible to per-thread alias analysis
// (R5 miscompiled without it). DS pipe runs a wave's LDS ops in order.
#define WAVE_LDS_FENCE()  do { asm volatile("" ::: "memory"); \
                               __builtin_amdgcn_wave_barrier(); } while (0)

__global__ __launch_bounds__(THREADS, 1) void
local_energy_coop(const float* __restrict__ F,
                  const float* __restrict__ bond_type,   // 15 x 2
                  const float* __restrict__ angle_type,  // 13 x 2
                  const float* __restrict__ tor_type,    // 25 x 2
                  const int*   __restrict__ multiplicity,// 25
                  const float* __restrict__ opt_pars,    // 47
                  float*       __restrict__ ws,          // 3 coord planes [B][4096]
                  float*       __restrict__ out)         // B x 3
{
    __shared__ float scx[N_ATOMS];
    __shared__ float scy[N_ATOMS];
    __shared__ float scz[N_ATOMS];
    __shared__ __align__(16) float4 scr[WAVES][SCR_F4];   // 68 KB
    __shared__ unsigned short sbB[2080 * 3];
    __shared__ unsigned short sbA[1560 * 4];
    __shared__ unsigned short sbT[1248 * 5];
    __shared__ float sbt[30], sat[26], stt[50], smu[25];
    __shared__ float sred[WAVES * 3];

    const int b   = blockIdx.x;
    const int x   = b & 7;             // XCD slot (twins share it -> L2-local exchange)
    const int g   = b >> 3;            // 0..31
    const int s   = (g & 15) * 8 + x;  // sample 0..127
    const int p   = g >> 4;            // twin 0..1
    const int tid = threadIdx.x;
    const int w   = tid >> 6;
    const int l   = tid & 63;
    const size_t sbase = (size_t)s * FSTRIDE;
    const int d = (int)(sbase & 3);
    const float4* __restrict__ F4 = (const float4*)F;

    if (tid < 30)                      sbt[tid]       = bond_type[tid];
    else if (tid >= 32 && tid < 58)    sat[tid - 32]  = angle_type[tid - 32];
    else if (tid >= 64 && tid < 114)   stt[tid - 64]  = tor_type[tid - 64];
    else if (tid >= 128 && tid < 153)  smu[tid - 128] = (float)multiplicity[tid - 128];

    float* const swf = (float*)scr[w];

    // Phase-A halves: p0 tiles [0,52), p1 [52,103). No twin redundancy.
    const int Alo = p ? 52 : 0;
    const int Ahi = p ? 103 : 52;
    const int cnt_b = p ? 2015 : 2080;   // bonds buffered (tile102: 15)
    const int cnt_a = p ? 1530 : 1560;
    const int cnt_t = p ? 1224 : 1248;

    // ============ Phase A: stream OWN tiles — coords + index buffering ============
    {
        const int nq = (d + TILE_F + 3) >> 2;
        float4 cur[5];
        int t = Alo + w;
        {
            const size_t q0 = (sbase + (size_t)t * TILE_F) >> 2;
            #pragma unroll
            for (int i = 0; i < 5; ++i) {
                const int k = l + 64 * i;
                cur[i] = (k < nq) ? F4[q0 + k] : make_float4(0.f, 0.f, 0.f, 0.f);
            }
        }
        for (; t < Ahi; t += WAVES) {
            const int tn = t + WAVES;
            float4 nxt[5];
            #pragma unroll
            for (int i = 0; i < 5; ++i) nxt[i] = make_float4(0.f, 0.f, 0.f, 0.f);
            if (tn < Ahi) {
                const size_t q0 = (sbase + (size_t)tn * TILE_F) >> 2;
                #pragma unroll
                for (int i = 0; i < 5; ++i) {
                    const int k = l + 64 * i;
                    if (k < nq) nxt[i] = F4[q0 + k];
                }
            }
            #pragma unroll
            for (int i = 0; i < 4; ++i) scr[w][l + 64 * i] = cur[i];
            if (l < 15) scr[w][l + 256] = cur[4];
            WAVE_LDS_FENCE();

            const int lt = t - Alo;
            int nat = N_ATOMS - 40 * t; nat = (nat > 40) ? 40 : nat;
            if (l < nat) {
                const int base = d + 27 * l;
                const int atom = 40 * t + l;
                scx[atom] = swf[base + 5];
                scy[atom] = swf[base + 14];
                scz[atom] = swf[base + 23];
            }
            int nb = NB - 40 * t; nb = (nb > 40) ? 40 : nb;
            if (l < nb) {
                const int sl = (lt * 40 + l) * 3;
                const int base = d + 27 * l;
                sbB[sl + 0] = (unsigned short)(int)swf[base + 6];
                sbB[sl + 1] = (unsigned short)(int)swf[base + 15];
                sbB[sl + 2] = (unsigned short)(int)swf[base + 24];
            }
            if (l < 30) {
                const int sl = (lt * 30 + l) * 4;
                const int base = d + 36 * l;
                sbA[sl + 0] = (unsigned short)(int)swf[base + 7];
                sbA[sl + 1] = (unsigned short)(int)swf[base + 16];
                sbA[sl + 2] = (unsigned short)(int)swf[base + 25];
                sbA[sl + 3] = (unsigned short)(int)swf[base + 34];
            }
            if (l < 24) {
                const int sl = (lt * 24 + l) * 5;
                const int base = d + 45 * l;
                sbT[sl + 0] = (unsigned short)(int)swf[base + 8];
                sbT[sl + 1] = (unsigned short)(int)swf[base + 17];
                sbT[sl + 2] = (unsigned short)(int)swf[base + 26];
                sbT[sl + 3] = (unsigned short)(int)swf[base + 35];
                sbT[sl + 4] = (unsigned short)(int)swf[base + 44];
            }
            WAVE_LDS_FENCE();
            #pragma unroll
            for (int i = 0; i < 5; ++i) cur[i] = nxt[i];
        }
    }
    __syncthreads();

    // ============ Coord exchange through ws (L2-local, coalesced f4) ============
    {
        float4* __restrict__ wx = (float4*)(ws + 0 * PLANE + (size_t)s * N_ATOMS);
        float4* __restrict__ wy = (float4*)(ws + 1 * PLANE + (size_t)s * N_ATOMS);
        float4* __restrict__ wz = (float4*)(ws + 2 * PLANE + (size_t)s * N_ATOMS);
        const int own_lo4 = p ? 520 : 0;     // atom 2080 boundary, /4
        const int own_n4  = p ? 504 : 520;
        for (int i = tid; i < own_n4; i += THREADS) {
            wx[own_lo4 + i] = ((float4*)scx)[own_lo4 + i];
            wy[own_lo4 + i] = ((float4*)scy)[own_lo4 + i];
            wz[own_lo4 + i] = ((float4*)scz)[own_lo4 + i];
        }
        __threadfence();
        cg::this_grid().sync();
        const int oth_lo4 = p ? 0 : 520;
        const int oth_n4  = p ? 520 : 504;
        for (int i = tid; i < oth_n4; i += THREADS) {
            ((float4*)scx)[oth_lo4 + i] = wx[oth_lo4 + i];
            ((float4*)scy)[oth_lo4 + i] = wy[oth_lo4 + i];
            ((float4*)scz)[oth_lo4 + i] = wz[oth_lo4 + i];
        }
    }
    __syncthreads();

    float e_bond = 0.f, e_ang = 0.f, e_tor = 0.f;

    // ============ Phase B: stream tiles 103..170 — direct compute ============
    {
        const int tlo = p ? 137 : 103;
        const int thi = p ? 171 : 137;
        float4 cur[5];
        int t = tlo + w;
        {
            const size_t q0 = (sbase + (size_t)t * TILE_F) >> 2;
            const int nf = (FSTRIDE - t * TILE_F < TILE_F) ? FSTRIDE - t * TILE_F : TILE_F;
            const int nq = (d + nf + 3) >> 2;
            #pragma unroll
            for (int i = 0; i < 5; ++i) {
                const int k = l + 64 * i;
                cur[i] = (k < nq && q0 + k < TOTAL_F4) ? F4[q0 + k]
                                                       : make_float4(0.f, 0.f, 0.f, 0.f);
            }
        }
        for (; t < thi; t += WAVES) {
            const int tn = t + WAVES;
            float4 nxt[5];
            #pragma unroll
            for (int i = 0; i < 5; ++i) nxt[i] = make_float4(0.f, 0.f, 0.f, 0.f);
            if (tn < thi) {
                const size_t q0 = (sbase + (size_t)tn * TILE_F) >> 2;
                const int nf = (FSTRIDE - tn * TILE_F < TILE_F) ? FSTRIDE - tn * TILE_F : TILE_F;
                const int nq = (d + nf + 3) >> 2;
                #pragma unroll
                for (int i = 0; i < 5; ++i) {
                    const int k = l + 64 * i;
                    if (k < nq && q0 + k < TOTAL_F4) nxt[i] = F4[q0 + k];
                }
            }
            #pragma unroll
            for (int i = 0; i < 4; ++i) scr[w][l + 64 * i] = cur[i];
            if (l < 15) scr[w][l + 256] = cur[4];
            WAVE_LDS_FENCE();

            int na = NA - 30 * t; na = (na > 30) ? 30 : na;
            if (l < na) {
                const int base = d + 36 * l;
                const int a0 = (int)swf[base + 7];
                const int a1 = (int)swf[base + 16];
                const int a2 = (int)swf[base + 25];
                const int at = (int)swf[base + 34];
                const float v1x = scx[a0] - scx[a1];
                const float v1y = scy[a0] - scy[a1];
                const float v1z = scz[a0] - scz[a1];
                const float v2x = scx[a2] - scx[a1];
                const float v2y = scy[a2] - scy[a1];
                const float v2z = scz[a2] - scz[a1];
                const float d12 = v1x*v2x + v1y*v2y + v1z*v2z;
                const float n1  = sqrtf(v1x*v1x + v1y*v1y + v1z*v1z + EPSV);
                const float n2  = sqrtf(v2x*v2x + v2y*v2y + v2z*v2z + EPSV);
                float cosang = d12 / (n1 * n2);
                cosang = fminf(fmaxf(cosang, -1.0f + 1e-6f), 1.0f - 1e-6f);
                const float t0 = acosf(cosang) - sat[at * 2 + 1];
                e_ang += sat[at * 2 + 0] * t0 * t0;
            }

            int ntr = NT - 24 * t; ntr = (ntr > 24) ? 24 : ntr;
            if (l < ntr) {
                const int base = d + 45 * l;
                const int ai = (int)swf[base + 8];
                const int aj = (int)swf[base + 17];
                const int ak = (int)swf[base + 26];
                const int al = (int)swf[base + 35];
                const int tt = (int)swf[base + 44];
                const float b1x = scx[aj] - scx[ai], b1y = scy[aj] - scy[ai], b1z = scz[aj] - scz[ai];
                const float b2x = scx[ak] - scx[aj], b2y = scy[ak] - scy[aj], b2z = scz[ak] - scz[aj];
                const float b3x = scx[al] - scx[ak], b3y = scy[al] - scy[ak], b3z = scz[al] - scz[ak];
                const float n1x = b1y*b2z - b1z*b2y;
                const float n1y = b1z*b2x - b1x*b2z;
                const float n1z = b1x*b2y - b1y*b2x;
                const float n2x = b2y*b3z - b2z*b3y;
                const float n2y = b2z*b3x - b2x*b3z;
                const float n2z = b2x*b3y - b2y*b3x;
                const float inv = 1.0f / sqrtf(b2x*b2x + b2y*b2y + b2z*b2z + EPSV);
                const float bnx = b2x * inv, bny = b2y * inv, bnz = b2z * inv;
                const float m1x = n1y*bnz - n1z*bny;
                const float m1y = n1z*bnx - n1x*bnz;
                const float m1z = n1x*bny - n1y*bnx;
                const float phi = atan2f(m1x*n2x + m1y*n2y + m1z*n2z,
                                         n1x*n2x + n1y*n2y + n1z*n2z);
                e_tor += stt[tt * 2 + 0] * (1.0f + cosf(smu[tt] * phi - stt[tt * 2 + 1]));
            }

            WAVE_LDS_FENCE();
            #pragma unroll
            for (int i = 0; i < 5; ++i) cur[i] = nxt[i];
        }
    }

    // ============ Phase C: buffered compute (pure LDS + VALU) ============
    for (int i = tid; i < cnt_b; i += THREADS) {
        const int a0 = sbB[3 * i + 0];
        const int a1 = sbB[3 * i + 1];
        const int bt = sbB[3 * i + 2];
        const float dx = scx[a0] - scx[a1];
        const float dy = scy[a0] - scy[a1];
        const float dz = scz[a0] - scz[a1];
        const float r  = sqrtf(dx*dx + dy*dy + dz*dz + EPSV);
        const float t0 = r - sbt[bt * 2 + 1];
        e_bond += sbt[bt * 2 + 0] * t0 * t0;
    }
    for (int i = tid; i < cnt_a; i += THREADS) {
        const int a0 = sbA[4 * i + 0];
        const int a1 = sbA[4 * i + 1];
        const int a2 = sbA[4 * i + 2];
        const int at = sbA[4 * i + 3];
        const float v1x = scx[a0] - scx[a1];
        const float v1y = scy[a0] - scy[a1];
        const float v1z = scz[a0] - scz[a1];
        const float v2x = scx[a2] - scx[a1];
        const float v2y = scy[a2] - scy[a1];
        const float v2z = scz[a2] - scz[a1];
        const float d12 = v1x*v2x + v1y*v2y + v1z*v2z;
        const float n1  = sqrtf(v1x*v1x + v1y*v1y + v1z*v1z + EPSV);
        const float n2  = sqrtf(v2x*v2x + v2y*v2y + v2z*v2z + EPSV);
        float cosang = d12 / (n1 * n2);
        cosang = fminf(fmaxf(cosang, -1.0f + 1e-6f), 1.0f - 1e-6f);
        const float t0 = acosf(cosang) - sat[at * 2 + 1];
        e_ang += sat[at * 2 + 0] * t0 * t0;
    }
    for (int i = tid; i < cnt_t; i += THREADS) {
        const int ai = sbT[5 * i + 0];
        const int aj = sbT[5 * i + 1];
        const int ak = sbT[5 * i + 2];
        const int al = sbT[5 * i + 3];
        const int tt = sbT[5 * i + 4];
        const float b1x = scx[aj] - scx[ai], b1y = scy[aj] - scy[ai], b1z = scz[aj] - scz[ai];
        const float b2x = scx[ak] - scx[aj], b2y = scy[ak] - scy[aj], b2z = scz[ak] - scz[aj];
        const float b3x = scx[al] - scx[ak], b3y = scy[al] - scy[ak], b3z = scz[al] - scz[ak];
        const float n1x = b1y*b2z - b1z*b2y;
        const float n1y = b1z*b2x - b1x*b2z;
        const float n1z = b1x*b2y - b1y*b2x;
        const float n2x = b2y*b3z - b2z*b3y;
        const float n2y = b2z*b3x - b2x*b3z;
        const float n2z = b2x*b3y - b2y*b3x;
        const float inv = 1.0f / sqrtf(b2x*b2x + b2y*b2y + b2z*b2z + EPSV);
        const float bnx = b2x * inv, bny = b2y * inv, bnz = b2z * inv;
        const float m1x = n1y*bnz - n1z*bny;
        const float m1y = n1z*bnx - n1x*bnz;
        const float m1z = n1x*bny - n1y*bnx;
        const float phi = atan2f(m1x*n2x + m1y*n2y + m1z*n2z,
                                 n1x*n2x + n1y*n2y + n1z*n2z);
        e_tor += stt[tt * 2 + 0] * (1.0f + cosf(smu[tt] * phi - stt[tt * 2 + 1]));
    }

    // ---- reduction ----
    for (int off = 32; off > 0; off >>= 1) {
        e_bond += __shfl_down(e_bond, off);
        e_ang  += __shfl_down(e_ang,  off);
        e_tor  += __shfl_down(e_tor,  off);
    }
    if (l == 0) {
        sred[w * 3 + 0] = e_bond;
        sred[w * 3 + 1] = e_ang;
        sred[w * 3 + 2] = e_tor;
    }
    __syncthreads();
    if (tid == 0) {
        float eb = 0.f, ea = 0.f, et = 0.f;
        for (int i = 0; i < WAVES; ++i) {
            eb += sred[i * 3 + 0];
            ea += sred[i * 3 + 1];
            et += sred[i * 3 + 2];
        }
        atomicAdd(&out[s * 3 + 0], opt_pars[0] * eb);
        atomicAdd(&out[s * 3 + 1], opt_pars[1] * ea);
        atomicAdd(&out[s * 3 + 2], opt_pars[2] * et);
    }
}

extern "C" void kernel_launch(void* const* d_in, const int* in_sizes, int n_in,
                              void* d_out, int out_size, void* d_ws, size_t ws_size,
                              hipStream_t stream) {
    const float* F            = (const float*)d_in[0];
    // d_in[1] = lengths (constant, unused)
    const float* bond_type    = (const float*)d_in[2];
    const float* angle_type   = (const float*)d_in[3];
    const float* tor_type     = (const float*)d_in[4];
    const int*   multiplicity = (const int*)  d_in[5];
    const float* opt_pars     = (const float*)d_in[6];
    float* out = (float*)d_out;
    float* ws  = (float*)d_ws;

    hipMemsetAsync(out, 0, (size_t)out_size * sizeof(float), stream);

    void* args[] = { (void*)&F, (void*)&bond_type, (void*)&angle_type,
                     (void*)&tor_type, (void*)&multiplicity, (void*)&opt_pars,
                     (void*)&ws, (void*)&out };
    hipLaunchCooperativeKernel((const void*)local_energy_coop,
                               dim3(GRID), dim3(THREADS), args, 0, stream);
}

// Round 10
// 157.827 us; speedup vs baseline: 1.8989x; 1.8989x over previous
//
#include <hip/hip_runtime.h>
#include <math.h>

#define BATCH      128
#define N_ATOMS    4096
#define NB         4095
#define NA         4094
#define NT         4093
#define FSTRIDE    184185              // floats per sample (odd!)
#define TOTAL_F4   5893920u            // 128*184185/4 (exact)
#define EPSV       1e-8f
#define THREADS    1024
#define WAVES      16
#define TILE_F     1080                // lcm-aligned: 40 bonds / 30 angles / 24 tors / 40 atoms
#define NTILES     171                 // ceil(184185/1080)
#define ATILES     103                 // tiles 0..102: ALL coords, ALL bonds, angles 0..3089, tors 0..2471
#define SCR_F4     272

// Zero-cost compiler fence for the wave-private LDS scratch round-trip.
// Cross-lane store->read dep is invisible to per-thread alias analysis
// (R5 miscompiled without it). DS pipe runs a wave's LDS ops in order.
#define WAVE_LDS_FENCE()  do { asm volatile("" ::: "memory"); \
                               __builtin_amdgcn_wave_barrier(); } while (0)

__global__ __launch_bounds__(THREADS, 1) void
local_energy_fused(const float* __restrict__ F,
                   const float* __restrict__ bond_type,   // 15 x 2
                   const float* __restrict__ angle_type,  // 13 x 2
                   const float* __restrict__ tor_type,    // 25 x 2
                   const int*   __restrict__ multiplicity,// 25
                   const float* __restrict__ opt_pars,    // 47
                   float*       __restrict__ out)         // B x 3
{
    __shared__ float scx[N_ATOMS];
    __shared__ float scy[N_ATOMS];
    __shared__ float scz[N_ATOMS];
    __shared__ __align__(16) float4 scr[WAVES][SCR_F4];   // 68 KB
    __shared__ unsigned short sbB[2080 * 3];
    __shared__ unsigned short sbA[1560 * 4];
    __shared__ unsigned short sbT[1248 * 5];
    __shared__ float sbt[30], sat[26], stt[50], smu[25];
    __shared__ float sred[WAVES * 3];

    const int b   = blockIdx.x;
    const int x   = b & 7;             // XCD slot
    const int g   = b >> 3;            // 0..31
    const int s   = (g & 15) * 8 + x;  // sample 0..127, XCD-pinned
    const int p   = g >> 4;            // twin 0..1
    const int tid = threadIdx.x;
    const int w   = tid >> 6;
    const int l   = tid & 63;
    const size_t sbase = (size_t)s * FSTRIDE;
    const int d = (int)(sbase & 3);
    const float4* __restrict__ F4 = (const float4*)F;

    if (tid < 30)                      sbt[tid]       = bond_type[tid];
    else if (tid >= 32 && tid < 58)    sat[tid - 32]  = angle_type[tid - 32];
    else if (tid >= 64 && tid < 114)   stt[tid - 64]  = tor_type[tid - 64];
    else if (tid >= 128 && tid < 153)  smu[tid - 128] = (float)multiplicity[tid - 128];

    float* const swf = (float*)scr[w];

    // index-buffering split: p0 tiles [0,51), p1 [51,103)
    const int Alo = p ? 51 : 0;
    const int Ahi = p ? 103 : 51;
    const int cnt_b = p ? 2055 : 2040;
    const int cnt_a = p ? 1560 : 1530;
    const int cnt_t = p ? 1248 : 1224;

    // ==== Phase A: stream tiles 0..102 (coords + index buffering), DEPTH-2 prefetch ====
    {
        const int nq = (d + TILE_F + 3) >> 2;        // uniform: all phase-A tiles are full
        float4 cur[5], nx1[5];
        int t = w;
        {   // load tile t
            const size_t q0 = (sbase + (size_t)t * TILE_F) >> 2;
            #pragma unroll
            for (int i = 0; i < 5; ++i) {
                const int k = l + 64 * i;
                cur[i] = (k < nq) ? F4[q0 + k] : make_float4(0.f, 0.f, 0.f, 0.f);
            }
        }
        {   // load tile t+WAVES
            const int t1 = t + WAVES;
            #pragma unroll
            for (int i = 0; i < 5; ++i) nx1[i] = make_float4(0.f, 0.f, 0.f, 0.f);
            if (t1 < ATILES) {
                const size_t q0 = (sbase + (size_t)t1 * TILE_F) >> 2;
                #pragma unroll
                for (int i = 0; i < 5; ++i) {
                    const int k = l + 64 * i;
                    if (k < nq) nx1[i] = F4[q0 + k];
                }
            }
        }
        for (; t < ATILES; t += WAVES) {
            const int t2 = t + 2 * WAVES;
            float4 nx2[5];
            #pragma unroll
            for (int i = 0; i < 5; ++i) nx2[i] = make_float4(0.f, 0.f, 0.f, 0.f);
            if (t2 < ATILES) {
                const size_t q0 = (sbase + (size_t)t2 * TILE_F) >> 2;
                #pragma unroll
                for (int i = 0; i < 5; ++i) {
                    const int k = l + 64 * i;
                    if (k < nq) nx2[i] = F4[q0 + k];
                }
            }
            #pragma unroll
            for (int i = 0; i < 4; ++i) scr[w][l + 64 * i] = cur[i];
            if (l < 15) scr[w][l + 256] = cur[4];
            WAVE_LDS_FENCE();                        // RAW: stores -> cross-lane reads

            const int lt = t - Alo;
            int nat = N_ATOMS - 40 * t; nat = (nat > 40) ? 40 : nat;
            if (l < nat) {
                const int base = d + 27 * l;
                const int atom = 40 * t + l;
                scx[atom] = swf[base + 5];
                scy[atom] = swf[base + 14];
                scz[atom] = swf[base + 23];
            }
            if (t >= Alo && t < Ahi) {               // wave-uniform branch
                int nb = NB - 40 * t; nb = (nb > 40) ? 40 : nb;
                if (l < nb) {
                    const int sl = (lt * 40 + l) * 3;
                    const int base = d + 27 * l;
                    sbB[sl + 0] = (unsigned short)(int)swf[base + 6];
                    sbB[sl + 1] = (unsigned short)(int)swf[base + 15];
                    sbB[sl + 2] = (unsigned short)(int)swf[base + 24];
                }
                if (l < 30) {
                    const int sl = (lt * 30 + l) * 4;
                    const int base = d + 36 * l;
                    sbA[sl + 0] = (unsigned short)(int)swf[base + 7];
                    sbA[sl + 1] = (unsigned short)(int)swf[base + 16];
                    sbA[sl + 2] = (unsigned short)(int)swf[base + 25];
                    sbA[sl + 3] = (unsigned short)(int)swf[base + 34];
                }
                if (l < 24) {
                    const int sl = (lt * 24 + l) * 5;
                    const int base = d + 45 * l;
                    sbT[sl + 0] = (unsigned short)(int)swf[base + 8];
                    sbT[sl + 1] = (unsigned short)(int)swf[base + 17];
                    sbT[sl + 2] = (unsigned short)(int)swf[base + 26];
                    sbT[sl + 3] = (unsigned short)(int)swf[base + 35];
                    sbT[sl + 4] = (unsigned short)(int)swf[base + 44];
                }
            }
            WAVE_LDS_FENCE();                        // WAR: reads -> next iter stores
            #pragma unroll
            for (int i = 0; i < 5; ++i) { cur[i] = nx1[i]; nx1[i] = nx2[i]; }
        }
    }
    __syncthreads();

    float e_bond = 0.f, e_ang = 0.f, e_tor = 0.f;

    // ==== Phase B: stream tiles 103..170 — direct compute (depth-1: only ~2 iters/wave) ====
    {
        const int tlo = p ? 137 : 103;
        const int thi = p ? 171 : 137;
        float4 cur[5];
        int t = tlo + w;
        {
            const size_t q0 = (sbase + (size_t)t * TILE_F) >> 2;
            const int nf = (FSTRIDE - t * TILE_F < TILE_F) ? FSTRIDE - t * TILE_F : TILE_F;
            const int nq = (d + nf + 3) >> 2;
            #pragma unroll
            for (int i = 0; i < 5; ++i) {
                const int k = l + 64 * i;
                cur[i] = (k < nq && q0 + k < TOTAL_F4) ? F4[q0 + k]
                                                       : make_float4(0.f, 0.f, 0.f, 0.f);
            }
        }
        for (; t < thi; t += WAVES) {
            const int tn = t + WAVES;
            float4 nxt[5];
            #pragma unroll
            for (int i = 0; i < 5; ++i) nxt[i] = make_float4(0.f, 0.f, 0.f, 0.f);
            if (tn < thi) {
                const size_t q0 = (sbase + (size_t)tn * TILE_F) >> 2;
                const int nf = (FSTRIDE - tn * TILE_F < TILE_F) ? FSTRIDE - tn * TILE_F : TILE_F;
                const int nq = (d + nf + 3) >> 2;
                #pragma unroll
                for (int i = 0; i < 5; ++i) {
                    const int k = l + 64 * i;
                    if (k < nq && q0 + k < TOTAL_F4) nxt[i] = F4[q0 + k];
                }
            }
            #pragma unroll
            for (int i = 0; i < 4; ++i) scr[w][l + 64 * i] = cur[i];
            if (l < 15) scr[w][l + 256] = cur[4];
            WAVE_LDS_FENCE();

            int na = NA - 30 * t; na = (na > 30) ? 30 : na;
            if (l < na) {
                const int base = d + 36 * l;
                const int a0 = (int)swf[base + 7];
                const int a1 = (int)swf[base + 16];
                const int a2 = (int)swf[base + 25];
                const int at = (int)swf[base + 34];
                const float v1x = scx[a0] - scx[a1];
                const float v1y = scy[a0] - scy[a1];
                const float v1z = scz[a0] - scz[a1];
                const float v2x = scx[a2] - scx[a1];
                const float v2y = scy[a2] - scy[a1];
                const float v2z = scz[a2] - scz[a1];
                const float d12 = v1x*v2x + v1y*v2y + v1z*v2z;
                const float n1  = sqrtf(v1x*v1x + v1y*v1y + v1z*v1z + EPSV);
                const float n2  = sqrtf(v2x*v2x + v2y*v2y + v2z*v2z + EPSV);
                float cosang = d12 / (n1 * n2);
                cosang = fminf(fmaxf(cosang, -1.0f + 1e-6f), 1.0f - 1e-6f);
                const float t0 = acosf(cosang) - sat[at * 2 + 1];
                e_ang += sat[at * 2 + 0] * t0 * t0;
            }

            int ntr = NT - 24 * t; ntr = (ntr > 24) ? 24 : ntr;
            if (l < ntr) {
                const int base = d + 45 * l;
                const int ai = (int)swf[base + 8];
                const int aj = (int)swf[base + 17];
                const int ak = (int)swf[base + 26];
                const int al = (int)swf[base + 35];
                const int tt = (int)swf[base + 44];
                const float b1x = scx[aj] - scx[ai], b1y = scy[aj] - scy[ai], b1z = scz[aj] - scz[ai];
                const float b2x = scx[ak] - scx[aj], b2y = scy[ak] - scy[aj], b2z = scz[ak] - scz[aj];
                const float b3x = scx[al] - scx[ak], b3y = scy[al] - scy[ak], b3z = scz[al] - scz[ak];
                const float n1x = b1y*b2z - b1z*b2y;
                const float n1y = b1z*b2x - b1x*b2z;
                const float n1z = b1x*b2y - b1y*b2x;
                const float n2x = b2y*b3z - b2z*b3y;
                const float n2y = b2z*b3x - b2x*b3z;
                const float n2z = b2x*b3y - b2y*b3x;
                const float inv = 1.0f / sqrtf(b2x*b2x + b2y*b2y + b2z*b2z + EPSV);
                const float bnx = b2x * inv, bny = b2y * inv, bnz = b2z * inv;
                const float m1x = n1y*bnz - n1z*bny;
                const float m1y = n1z*bnx - n1x*bnz;
                const float m1z = n1x*bny - n1y*bnx;
                const float phi = atan2f(m1x*n2x + m1y*n2y + m1z*n2z,
                                         n1x*n2x + n1y*n2y + n1z*n2z);
                e_tor += stt[tt * 2 + 0] * (1.0f + cosf(smu[tt] * phi - stt[tt * 2 + 1]));
            }

            WAVE_LDS_FENCE();
            #pragma unroll
            for (int i = 0; i < 5; ++i) cur[i] = nxt[i];
        }
    }

    // ==== Phase C: buffered compute (pure LDS + VALU) ====
    for (int i = tid; i < cnt_b; i += THREADS) {
        const int a0 = sbB[3 * i + 0];
        const int a1 = sbB[3 * i + 1];
        const int bt = sbB[3 * i + 2];
        const float dx = scx[a0] - scx[a1];
        const float dy = scy[a0] - scy[a1];
        const float dz = scz[a0] - scz[a1];
        const float r  = sqrtf(dx*dx + dy*dy + dz*dz + EPSV);
        const float t0 = r - sbt[bt * 2 + 1];
        e_bond += sbt[bt * 2 + 0] * t0 * t0;
    }
    for (int i = tid; i < cnt_a; i += THREADS) {
        const int a0 = sbA[4 * i + 0];
        const int a1 = sbA[4 * i + 1];
        const int a2 = sbA[4 * i + 2];
        const int at = sbA[4 * i + 3];
        const float v1x = scx[a0] - scx[a1];
        const float v1y = scy[a0] - scy[a1];
        const float v1z = scz[a0] - scz[a1];
        const float v2x = scx[a2] - scx[a1];
        const float v2y = scy[a2] - scy[a1];
        const float v2z = scz[a2] - scz[a1];
        const float d12 = v1x*v2x + v1y*v2y + v1z*v2z;
        const float n1  = sqrtf(v1x*v1x + v1y*v1y + v1z*v1z + EPSV);
        const float n2  = sqrtf(v2x*v2x + v2y*v2y + v2z*v2z + EPSV);
        float cosang = d12 / (n1 * n2);
        cosang = fminf(fmaxf(cosang, -1.0f + 1e-6f), 1.0f - 1e-6f);
        const float t0 = acosf(cosang) - sat[at * 2 + 1];
        e_ang += sat[at * 2 + 0] * t0 * t0;
    }
    for (int i = tid; i < cnt_t; i += THREADS) {
        const int ai = sbT[5 * i + 0];
        const int aj = sbT[5 * i + 1];
        const int ak = sbT[5 * i + 2];
        const int al = sbT[5 * i + 3];
        const int tt = sbT[5 * i + 4];
        const float b1x = scx[aj] - scx[ai], b1y = scy[aj] - scy[ai], b1z = scz[aj] - scz[ai];
        const float b2x = scx[ak] - scx[aj], b2y = scy[ak] - scy[aj], b2z = scz[ak] - scz[aj];
        const float b3x = scx[al] - scx[ak], b3y = scy[al] - scy[ak], b3z = scz[al] - scz[ak];
        const float n1x = b1y*b2z - b1z*b2y;
        const float n1y = b1z*b2x - b1x*b2z;
        const float n1z = b1x*b2y - b1y*b2x;
        const float n2x = b2y*b3z - b2z*b3y;
        const float n2y = b2z*b3x - b2x*b3z;
        const float n2z = b2x*b3y - b2y*b3x;
        const float inv = 1.0f / sqrtf(b2x*b2x + b2y*b2y + b2z*b2z + EPSV);
        const float bnx = b2x * inv, bny = b2y * inv, bnz = b2z * inv;
        const float m1x = n1y*bnz - n1z*bny;
        const float m1y = n1z*bnx - n1x*bnz;
        const float m1z = n1x*bny - n1y*bnx;
        const float phi = atan2f(m1x*n2x + m1y*n2y + m1z*n2z,
                                 n1x*n2x + n1y*n2y + n1z*n2z);
        e_tor += stt[tt * 2 + 0] * (1.0f + cosf(smu[tt] * phi - stt[tt * 2 + 1]));
    }

    // ---- reduction ----
    for (int off = 32; off > 0; off >>= 1) {
        e_bond += __shfl_down(e_bond, off);
        e_ang  += __shfl_down(e_ang,  off);
        e_tor  += __shfl_down(e_tor,  off);
    }
    if (l == 0) {
        sred[w * 3 + 0] = e_bond;
        sred[w * 3 + 1] = e_ang;
        sred[w * 3 + 2] = e_tor;
    }
    __syncthreads();
    if (tid == 0) {
        float eb = 0.f, ea = 0.f, et = 0.f;
        for (int i = 0; i < WAVES; ++i) {
            eb += sred[i * 3 + 0];
            ea += sred[i * 3 + 1];
            et += sred[i * 3 + 2];
        }
        atomicAdd(&out[s * 3 + 0], opt_pars[0] * eb);
        atomicAdd(&out[s * 3 + 1], opt_pars[1] * ea);
        atomicAdd(&out[s * 3 + 2], opt_pars[2] * et);
    }
}

extern "C" void kernel_launch(void* const* d_in, const int* in_sizes, int n_in,
                              void* d_out, int out_size, void* d_ws, size_t ws_size,
                              hipStream_t stream) {
    const float* F            = (const float*)d_in[0];
    // d_in[1] = lengths (constant, unused)
    const float* bond_type    = (const float*)d_in[2];
    const float* angle_type   = (const float*)d_in[3];
    const float* tor_type     = (const float*)d_in[4];
    const int*   multiplicity = (const int*)  d_in[5];
    const float* opt_pars     = (const float*)d_in[6];
    float* out = (float*)d_out;

    hipMemsetAsync(out, 0, (size_t)out_size * sizeof(float), stream);

    local_energy_fused<<<dim3(BATCH * 2), dim3(THREADS), 0, stream>>>(
        F, bond_type, angle_type, tor_type, multiplicity, opt_pars, out);
}

// Round 11
// 155.800 us; speedup vs baseline: 1.9236x; 1.0130x over previous
//
#include <hip/hip_runtime.h>
#include <math.h>

#define BATCH    128
#define N_ATOMS  4096
#define NB       4095
#define NA       4094
#define NT       4093
#define FSTRIDE  184185                // floats per sample
#define ROWS     20465                 // MAX_LEN rows of 9 floats
#define CROWS    12288                 // coord elements (3*N_ATOMS)
#define BROWS    12285                 // bond elements  (3*NB)
#define AROWS    16376                 // angle elements (4*NA)
#define EPSV     1e-8f
#define THREADS  1024
#define WAVES    16
#define TPR      120                   // rows per tile (2 rows per lane)

// 4-byte-aligned float4: VMEM multi-dword loads only need dword alignment on
// CDNA; cols 5..8 of row R are contiguous at float offset 9R+5 (mod-4 varies).
typedef float float4a __attribute__((ext_vector_type(4), aligned(4)));

__global__ __launch_bounds__(THREADS, 1) void
local_energy_v11(const float* __restrict__ F,
                 const float* __restrict__ bond_type,   // 15 x 2
                 const float* __restrict__ angle_type,  // 13 x 2
                 const float* __restrict__ tor_type,    // 25 x 2
                 const int*   __restrict__ multiplicity,// 25
                 const float* __restrict__ opt_pars,    // 47
                 float*       __restrict__ out)         // B x 3
{
    __shared__ float          scc[CROWS];   // coords in row order: atom a = scc[3a+c]
    __shared__ unsigned short sbB[BROWS + 1];
    __shared__ unsigned short sbA[AROWS];
    __shared__ unsigned short sbT[ROWS + 1];
    __shared__ float sbt[30], sat[26], stt[50], smu[25];
    __shared__ float sred[WAVES * 2];

    const int b   = blockIdx.x;
    const int x   = b & 7;             // XCD slot (twins share it -> L2 dedup of F stream)
    const int g   = b >> 3;            // 0..31
    const int s   = (g & 15) * 8 + x;  // sample 0..127
    const int p   = g >> 4;            // 0: torsions   1: bonds + angles
    const int tid = threadIdx.x;
    const int w   = tid >> 6;
    const int l   = tid & 63;
    const size_t sbase = (size_t)s * FSTRIDE;

    if (tid < 30)                      sbt[tid]       = bond_type[tid];
    else if (tid >= 32 && tid < 58)    sat[tid - 32]  = angle_type[tid - 32];
    else if (tid >= 64 && tid < 114)   stt[tid - 64]  = tor_type[tid - 64];
    else if (tid >= 128 && tid < 153)  smu[tid - 128] = (float)multiplicity[tid - 128];

    // ======== Phase A: stream rows, extract columns at stream order ========
    // Row R: one dwordx4 at 9R+5 gives (coord[R], bond[R], angle[R], tor[R]).
    // Element R of each column stream lands at LDS index R -- no divmod, no
    // staging, no cross-lane scratch, no fences. Lane l takes rows 120t+2l,+2l+1.
    const int tmax = p ? 137 : 171;    // p1 needs rows < AROWS only (137*120 >= 16376)
    for (int t = w; t < tmax; t += WAVES) {
        const int R0 = TPR * t + 2 * l;          // even
        const int R1 = R0 + 1;
        float4a v0, v1;
        const bool ok0 = (R0 < ROWS);
        const bool ok1 = (R1 < ROWS);
        if (ok0) v0 = *(const float4a*)(F + sbase + (size_t)9 * R0 + 5);
        if (ok1) v1 = *(const float4a*)(F + sbase + (size_t)9 * R1 + 5);

        // coords (CROWS even -> pairwise uniform)
        if (R1 < CROWS) {
            float2 c2; c2.x = v0.x; c2.y = v1.x;
            *(float2*)(scc + R0) = c2;
        }
        if (p) {
            // bonds (BROWS odd -> tail single)
            if (R1 < BROWS) {
                unsigned pk = (unsigned)(unsigned short)(int)v0.y
                            | ((unsigned)(unsigned short)(int)v1.y << 16);
                *(unsigned*)(sbB + R0) = pk;
            } else if (R0 < BROWS) {
                sbB[R0] = (unsigned short)(int)v0.y;
            }
            // angles (AROWS even)
            if (R1 < AROWS) {
                unsigned pk = (unsigned)(unsigned short)(int)v0.z
                            | ((unsigned)(unsigned short)(int)v1.z << 16);
                *(unsigned*)(sbA + R0) = pk;
            }
        } else {
            // torsions (ROWS odd -> tail single)
            if (ok1) {
                unsigned pk = (unsigned)(unsigned short)(int)v0.w
                            | ((unsigned)(unsigned short)(int)v1.w << 16);
                *(unsigned*)(sbT + R0) = pk;
            } else if (ok0) {
                sbT[R0] = (unsigned short)(int)v0.w;
            }
        }
    }
    __syncthreads();

    // ======== Phase B: compute from compact LDS ========
    float eA = 0.f, eB = 0.f;          // p0: eA=tor | p1: eA=bond, eB=angle
    if (p) {
        for (int i = tid; i < NB; i += THREADS) {
            const int a0 = sbB[3 * i + 0];
            const int a1 = sbB[3 * i + 1];
            const int bt = sbB[3 * i + 2];
            const float dx = scc[3 * a0 + 0] - scc[3 * a1 + 0];
            const float dy = scc[3 * a0 + 1] - scc[3 * a1 + 1];
            const float dz = scc[3 * a0 + 2] - scc[3 * a1 + 2];
            const float r  = sqrtf(dx * dx + dy * dy + dz * dz + EPSV);
            const float t0 = r - sbt[bt * 2 + 1];
            eA += sbt[bt * 2 + 0] * t0 * t0;
        }
        for (int i = tid; i < NA; i += THREADS) {
            const int a0 = sbA[4 * i + 0];
            const int a1 = sbA[4 * i + 1];
            const int a2 = sbA[4 * i + 2];
            const int at = sbA[4 * i + 3];
            const float v1x = scc[3 * a0 + 0] - scc[3 * a1 + 0];
            const float v1y = scc[3 * a0 + 1] - scc[3 * a1 + 1];
            const float v1z = scc[3 * a0 + 2] - scc[3 * a1 + 2];
            const float v2x = scc[3 * a2 + 0] - scc[3 * a1 + 0];
            const float v2y = scc[3 * a2 + 1] - scc[3 * a1 + 1];
            const float v2z = scc[3 * a2 + 2] - scc[3 * a1 + 2];
            const float d12 = v1x * v2x + v1y * v2y + v1z * v2z;
            const float n1  = sqrtf(v1x * v1x + v1y * v1y + v1z * v1z + EPSV);
            const float n2  = sqrtf(v2x * v2x + v2y * v2y + v2z * v2z + EPSV);
            float cosang = d12 / (n1 * n2);
            cosang = fminf(fmaxf(cosang, -1.0f + 1e-6f), 1.0f - 1e-6f);
            const float t0 = acosf(cosang) - sat[at * 2 + 1];
            eB += sat[at * 2 + 0] * t0 * t0;
        }
    } else {
        for (int i = tid; i < NT; i += THREADS) {
            const int ai = sbT[5 * i + 0];
            const int aj = sbT[5 * i + 1];
            const int ak = sbT[5 * i + 2];
            const int al = sbT[5 * i + 3];
            const int tt = sbT[5 * i + 4];
            const float b1x = scc[3*aj+0] - scc[3*ai+0];
            const float b1y = scc[3*aj+1] - scc[3*ai+1];
            const float b1z = scc[3*aj+2] - scc[3*ai+2];
            const float b2x = scc[3*ak+0] - scc[3*aj+0];
            const float b2y = scc[3*ak+1] - scc[3*aj+1];
            const float b2z = scc[3*ak+2] - scc[3*aj+2];
            const float b3x = scc[3*al+0] - scc[3*ak+0];
            const float b3y = scc[3*al+1] - scc[3*ak+1];
            const float b3z = scc[3*al+2] - scc[3*ak+2];
            const float n1x = b1y*b2z - b1z*b2y;
            const float n1y = b1z*b2x - b1x*b2z;
            const float n1z = b1x*b2y - b1y*b2x;
            const float n2x = b2y*b3z - b2z*b3y;
            const float n2y = b2z*b3x - b2x*b3z;
            const float n2z = b2x*b3y - b2y*b3x;
            const float inv = 1.0f / sqrtf(b2x*b2x + b2y*b2y + b2z*b2z + EPSV);
            const float bnx = b2x * inv, bny = b2y * inv, bnz = b2z * inv;
            const float m1x = n1y*bnz - n1z*bny;
            const float m1y = n1z*bnx - n1x*bnz;
            const float m1z = n1x*bny - n1y*bnx;
            const float phi = atan2f(m1x*n2x + m1y*n2y + m1z*n2z,
                                     n1x*n2x + n1y*n2y + n1z*n2z);
            eA += stt[tt * 2 + 0] * (1.0f + cosf(smu[tt] * phi - stt[tt * 2 + 1]));
        }
    }

    // ======== Reduction + disjoint plain stores (no memset/atomics needed) ====
    for (int off = 32; off > 0; off >>= 1) {
        eA += __shfl_down(eA, off);
        eB += __shfl_down(eB, off);
    }
    if (l == 0) {
        sred[w * 2 + 0] = eA;
        sred[w * 2 + 1] = eB;
    }
    __syncthreads();
    if (tid == 0) {
        float rA = 0.f, rB = 0.f;
        for (int i = 0; i < WAVES; ++i) { rA += sred[i * 2]; rB += sred[i * 2 + 1]; }
        if (p) {
            out[s * 3 + 0] = opt_pars[0] * rA;   // bonds
            out[s * 3 + 1] = opt_pars[1] * rB;   // angles
        } else {
            out[s * 3 + 2] = opt_pars[2] * rA;   // torsions
        }
    }
}

extern "C" void kernel_launch(void* const* d_in, const int* in_sizes, int n_in,
                              void* d_out, int out_size, void* d_ws, size_t ws_size,
                              hipStream_t stream) {
    const float* F            = (const float*)d_in[0];
    // d_in[1] = lengths (constant, unused)
    const float* bond_type    = (const float*)d_in[2];
    const float* angle_type   = (const float*)d_in[3];
    const float* tor_type     = (const float*)d_in[4];
    const int*   multiplicity = (const int*)  d_in[5];
    const float* opt_pars     = (const float*)d_in[6];
    float* out = (float*)d_out;

    // Every out element is written exactly once by plain stores (p1 -> [0],[1];
    // p0 -> [2]), so no memset / atomics are required.
    local_energy_v11<<<dim3(BATCH * 2), dim3(THREADS), 0, stream>>>(
        F, bond_type, angle_type, tor_type, multiplicity, opt_pars, out);
}